// Round 5
// baseline (304.509 us; speedup 1.0000x reference)
//
#include <hip/hip_runtime.h>
#include <hip/hip_bf16.h>

#define N_NODES  12288
#define N_FEAT   256
#define KDIM     128
#define N_GRAPHS 192
#define NMAX     112          // LDS fast-path max graph size (mean 64, std ~8)
#define KSTRIDE_U 68          // Kb LDS row stride in uints (272 B: staggered banks)
#define NSL      8            // row-slices per graph in attn_w_k

// qk_proj MFMA tile params
#define MT   32               // rows per block
#define XS_STRIDE_U 36        // X LDS row stride in u32 (72 bf16; 36%32=4 -> balanced)
#define WT_STRIDE_U 36        // Wt LDS row stride in u32

// workspace layout (bytes)
#define WS_STARTS 0
#define WS_WBUF   1024
#define WS_QG     (WS_WBUF + N_NODES * 4)             // fp32 Q [12288][128]
#define WS_KB     (WS_QG + N_NODES * KDIM * 4)        // bf16 K [12288][128] as u32[64]
#define WS_WT     (WS_KB + N_NODES * 64 * 4)          // bf16 Wt [256 n][256 k] as u32[128]

typedef __bf16 bf16x8 __attribute__((ext_vector_type(8)));
typedef float  f32x4  __attribute__((ext_vector_type(4)));

__device__ __forceinline__ unsigned bf16_rne(float f) {
  unsigned u = __float_as_uint(f);
  return (u + 0x7FFFu + ((u >> 16) & 1u)) >> 16;
}
__device__ __forceinline__ unsigned pack_bf16(float lo, float hi) {
  return bf16_rne(lo) | (bf16_rne(hi) << 16);
}
__device__ __forceinline__ float bf_lo(unsigned u) { return __uint_as_float(u << 16); }
__device__ __forceinline__ float bf_hi(unsigned u) { return __uint_as_float(u & 0xFFFF0000u); }

// ---------------------------------------------------------------------------
// Kernel 1: segment starts via binary search (batch is sorted).
// ---------------------------------------------------------------------------
__global__ __launch_bounds__(256) void seg_starts_k(const int* __restrict__ batch,
                                                    int* __restrict__ starts) {
  int g = threadIdx.x;
  if (g > N_GRAPHS) return;
  int lo = 0, hi = N_NODES;
  while (lo < hi) {
    int mid = (lo + hi) >> 1;
    if (batch[mid] < g) lo = mid + 1; else hi = mid;
  }
  starts[g] = lo;
}

// ---------------------------------------------------------------------------
// Kernel 1b: W pre-transpose to bf16.  Wt[n][k] packed u32 pairs (k, k+1).
// ---------------------------------------------------------------------------
__global__ __launch_bounds__(64) void wt_prep_k(const float* __restrict__ Wq,
                                                const float* __restrict__ Wk,
                                                unsigned* __restrict__ Wt) {
  const int n = blockIdx.x;
  const int t = threadIdx.x;
  const float* src = (n < KDIM) ? (Wq + n) : (Wk + (n - KDIM));
  float f0 = src[(4 * t + 0) * KDIM];
  float f1 = src[(4 * t + 1) * KDIM];
  float f2 = src[(4 * t + 2) * KDIM];
  float f3 = src[(4 * t + 3) * KDIM];
  Wt[n * 128 + 2 * t]     = pack_bf16(f0, f1);
  Wt[n * 128 + 2 * t + 1] = pack_bf16(f2, f3);
}

// ---------------------------------------------------------------------------
// Kernel 2: fused Q|K projection via bf16 MFMA (unchanged from R4).
// ---------------------------------------------------------------------------
__global__ __launch_bounds__(256) void qk_proj_k(const float* __restrict__ X,
                                                 const unsigned* __restrict__ Wt,
                                                 float* __restrict__ Qg,
                                                 unsigned* __restrict__ Kb) {
  __shared__ unsigned Xs_u[MT * XS_STRIDE_U];      // 4608 B
  __shared__ unsigned Ws_u[256 * WT_STRIDE_U];     // 36864 B

  const int tid  = threadIdx.x;
  const int lane = tid & 63;
  const int wv   = tid >> 6;
  const int r0   = blockIdx.x * MT;
  const int l15  = lane & 15;
  const int quad = lane >> 4;

  f32x4 acc[2][4];
#pragma unroll
  for (int mi = 0; mi < 2; mi++)
#pragma unroll
    for (int ni = 0; ni < 4; ni++) acc[mi][ni] = (f32x4){0.f, 0.f, 0.f, 0.f};

  for (int c = 0; c < 4; c++) {
    const int k0 = c * 64;
    if (c) __syncthreads();

    {
      const int row = tid >> 3, c8 = tid & 7;
      const float* xp = &X[(size_t)(r0 + row) * N_FEAT + k0 + c8 * 8];
      float4 a = *(const float4*)xp;
      float4 b = *(const float4*)(xp + 4);
      unsigned p0 = pack_bf16(a.x, a.y), p1 = pack_bf16(a.z, a.w);
      unsigned p2 = pack_bf16(b.x, b.y), p3 = pack_bf16(b.z, b.w);
      *(uint4*)&Xs_u[row * XS_STRIDE_U + c8 * 4] = make_uint4(p0, p1, p2, p3);
    }
#pragma unroll
    for (int it = 0; it < 8; it++) {
      const int i = tid + it * 256;
      const int n = i >> 3, c8 = i & 7;
      uint4 w = *(const uint4*)&Wt[n * 128 + k0 / 2 + c8 * 4];
      *(uint4*)&Ws_u[n * WT_STRIDE_U + c8 * 4] = w;
    }
    __syncthreads();

#pragma unroll
    for (int ks = 0; ks < 2; ks++) {
      const int ko = ks * 16 + quad * 4;
      bf16x8 a[2], b[4];
#pragma unroll
      for (int mi = 0; mi < 2; mi++)
        a[mi] = *(const bf16x8*)&Xs_u[(mi * 16 + l15) * XS_STRIDE_U + ko];
#pragma unroll
      for (int ni = 0; ni < 4; ni++)
        b[ni] = *(const bf16x8*)&Ws_u[(wv * 64 + ni * 16 + l15) * WT_STRIDE_U + ko];
#pragma unroll
      for (int mi = 0; mi < 2; mi++)
#pragma unroll
        for (int ni = 0; ni < 4; ni++)
          acc[mi][ni] = __builtin_amdgcn_mfma_f32_16x16x32_bf16(a[mi], b[ni], acc[mi][ni], 0, 0, 0);
    }
  }

  if (wv < 2) {
#pragma unroll
    for (int mi = 0; mi < 2; mi++)
#pragma unroll
      for (int ni = 0; ni < 4; ni++) {
        const int col = wv * 64 + ni * 16 + l15;
#pragma unroll
        for (int e = 0; e < 4; e++) {
          const int row = r0 + mi * 16 + quad * 4 + e;
          Qg[row * KDIM + col] = acc[mi][ni][e] * 0.0625f;
        }
      }
  } else {
#pragma unroll
    for (int mi = 0; mi < 2; mi++)
#pragma unroll
      for (int ni = 0; ni < 4; ni++) {
        const int col = (wv - 2) * 64 + ni * 16 + l15;
#pragma unroll
        for (int e = 0; e < 4; e++) {
          const int row = r0 + mi * 16 + quad * 4 + e;
          unsigned b = bf16_rne(acc[mi][ni][e]);
          unsigned partner = __shfl_xor((int)b, 1);
          if ((lane & 1) == 0)
            Kb[row * 64 + (col >> 1)] = b | (partner << 16);
        }
      }
  }
}

// ---------------------------------------------------------------------------
// Kernel 3: per-(graph, slice) column weights of softmax(QK^T).
// 8 slices/graph -> 1536 blocks x 256 thr. launch_bounds(256,4) caps VGPR at
// 128 (the m69 occupancy cliff at 140 VGPR cost R4 2x). Score accumulation
// split into 4 independent partials per column-half -> dep chain 256->64.
// ---------------------------------------------------------------------------
__global__ __launch_bounds__(256, 4) void attn_w_k(const int* __restrict__ starts,
                                                   const float* __restrict__ Qg,
                                                   const unsigned* __restrict__ Kb,
                                                   float* __restrict__ wbuf) {
  __shared__ unsigned Ks_u[NMAX * KSTRIDE_U];   // 30464 B
  __shared__ float    Qs[14 * 128];             // 7168 B
  __shared__ float    w_lds[4][128];            // 2048 B

  const int tid  = threadIdx.x;
  const int lane = tid & 63;
  const int wv   = tid >> 6;
  const int g    = blockIdx.x >> 3;
  const int qi   = blockIdx.x & 7;

  const int i0 = starts[g];
  const int n  = starts[g + 1] - i0;
  const float BIG = 1e30f;
  const bool fast = (n <= NMAX);
  if (!fast && qi != 0) return;

  float wacc0 = 0.f, wacc1 = 0.f;

  if (fast) {
    const int qlen = (n + NSL - 1) >> 3;
    const int q0 = i0 + qi * qlen;
    const int q1 = min(i0 + n, q0 + qlen);
    const int rcount = q1 - q0;
    if (rcount <= 0) return;   // uniform across block

    // ---- stage K (bf16) and Q slice (fp32) ----
    for (int idx = tid; idx < n * 16; idx += 256) {
      int j = idx >> 4, c = idx & 15;
      *(uint4*)&Ks_u[j * KSTRIDE_U + 4 * c] = *(const uint4*)&Kb[(i0 + j) * 64 + 4 * c];
    }
    for (int idx = tid; idx < rcount * 32; idx += 256) {
      int r = idx >> 5, c = idx & 31;
      *(float4*)&Qs[r * 128 + 4 * c] = *(const float4*)&Qg[(q0 + r) * KDIM + 4 * c];
    }
    __syncthreads();

    const int j2c = min(64 + lane, NMAX - 1);
    const unsigned* kp1 = &Ks_u[lane * KSTRIDE_U];
    const unsigned* kp2 = &Ks_u[j2c * KSTRIDE_U];

    for (int lr = wv; lr < rcount; lr += 4) {
      const float* qp = &Qs[lr * 128];
      float s0p[4] = {0.f, 0.f, 0.f, 0.f};
      float s1p[4] = {0.f, 0.f, 0.f, 0.f};
#pragma unroll
      for (int c = 0; c < 16; c++) {
        const int p = c & 3;   // partial-accumulator index: 4-way chain break
        float4 qa = *(const float4*)&qp[8 * c];
        float4 qb = *(const float4*)&qp[8 * c + 4];
        uint4 K1 = *(const uint4*)&kp1[4 * c];
        uint4 K2 = *(const uint4*)&kp2[4 * c];
        float a0 = s0p[p], a1 = s1p[p];
        a0 = fmaf(qa.x, bf_lo(K1.x), a0); a0 = fmaf(qa.y, bf_hi(K1.x), a0);
        a0 = fmaf(qa.z, bf_lo(K1.y), a0); a0 = fmaf(qa.w, bf_hi(K1.y), a0);
        a0 = fmaf(qb.x, bf_lo(K1.z), a0); a0 = fmaf(qb.y, bf_hi(K1.z), a0);
        a0 = fmaf(qb.z, bf_lo(K1.w), a0); a0 = fmaf(qb.w, bf_hi(K1.w), a0);
        a1 = fmaf(qa.x, bf_lo(K2.x), a1); a1 = fmaf(qa.y, bf_hi(K2.x), a1);
        a1 = fmaf(qa.z, bf_lo(K2.y), a1); a1 = fmaf(qa.w, bf_hi(K2.y), a1);
        a1 = fmaf(qb.x, bf_lo(K2.z), a1); a1 = fmaf(qb.y, bf_hi(K2.z), a1);
        a1 = fmaf(qb.z, bf_lo(K2.w), a1); a1 = fmaf(qb.w, bf_hi(K2.w), a1);
        s0p[p] = a0; s1p[p] = a1;
      }
      float s0 = (s0p[0] + s0p[1]) + (s0p[2] + s0p[3]);
      float s1 = (s1p[0] + s1p[1]) + (s1p[2] + s1p[3]);
      if (lane >= n)      s0 = -BIG;
      if (64 + lane >= n) s1 = -BIG;

      float m = fmaxf(s0, s1);
#pragma unroll
      for (int off = 32; off; off >>= 1) m = fmaxf(m, __shfl_xor(m, off));
      float e0 = __expf(s0 - m);
      float e1 = __expf(s1 - m);
      float l = e0 + e1;
#pragma unroll
      for (int off = 32; off; off >>= 1) l += __shfl_xor(l, off);
      float inv = 1.f / l;
      wacc0 += e0 * inv;
      wacc1 += e1 * inv;
    }
  } else {
    // ---- slow path: whole graph, global bf16 K, two-pass online softmax ----
    for (int lr = wv; lr < n; lr += 4) {
      const float* qp = &Qg[(i0 + lr) * KDIM];
      float m_run = -BIG, l_run = 0.f;
      for (int jb = 0; jb < n; jb += 64) {
        int j = jb + lane;
        int jc = min(j, n - 1);
        const unsigned* kp = &Kb[(i0 + jc) * 64];
        float s = 0.f;
        for (int c = 0; c < 16; c++) {
          float4 qa = *(const float4*)&qp[8 * c];
          float4 qb = *(const float4*)&qp[8 * c + 4];
          uint4 K1 = *(const uint4*)&kp[4 * c];
          s = fmaf(qa.x, bf_lo(K1.x), s); s = fmaf(qa.y, bf_hi(K1.x), s);
          s = fmaf(qa.z, bf_lo(K1.y), s); s = fmaf(qa.w, bf_hi(K1.y), s);
          s = fmaf(qb.x, bf_lo(K1.z), s); s = fmaf(qb.y, bf_hi(K1.z), s);
          s = fmaf(qb.z, bf_lo(K1.w), s); s = fmaf(qb.w, bf_hi(K1.w), s);
        }
        if (j >= n) s = -BIG;
        float mc = s;
        for (int off = 32; off; off >>= 1) mc = fmaxf(mc, __shfl_xor(mc, off));
        float m_new = fmaxf(m_run, mc);
        float lc = __expf(s - m_new);
        for (int off = 32; off; off >>= 1) lc += __shfl_xor(lc, off);
        l_run = l_run * __expf(m_run - m_new) + lc;
        m_run = m_new;
      }
      float inv = 1.f / l_run;
      for (int jb = 0; jb < n; jb += 64) {
        int j = jb + lane;
        int jc = min(j, n - 1);
        const unsigned* kp = &Kb[(i0 + jc) * 64];
        float s = 0.f;
        for (int c = 0; c < 16; c++) {
          float4 qa = *(const float4*)&qp[8 * c];
          float4 qb = *(const float4*)&qp[8 * c + 4];
          uint4 K1 = *(const uint4*)&kp[4 * c];
          s = fmaf(qa.x, bf_lo(K1.x), s); s = fmaf(qa.y, bf_hi(K1.x), s);
          s = fmaf(qa.z, bf_lo(K1.y), s); s = fmaf(qa.w, bf_hi(K1.y), s);
          s = fmaf(qb.x, bf_lo(K1.z), s); s = fmaf(qb.y, bf_hi(K1.z), s);
          s = fmaf(qb.z, bf_lo(K1.w), s); s = fmaf(qb.w, bf_hi(K1.w), s);
        }
        if (j < n) atomicAdd(&wbuf[i0 + j], __expf(s - m_run) * inv);
      }
    }
  }

  w_lds[wv][lane] = wacc0;
  w_lds[wv][64 + lane] = wacc1;
  __syncthreads();
  if (tid < 128) {
    float t = w_lds[0][tid] + w_lds[1][tid] + w_lds[2][tid] + w_lds[3][tid];
    if (tid < n && t != 0.f) atomicAdd(&wbuf[i0 + tid], t);
  }
}

// ---------------------------------------------------------------------------
// Kernel 4: out[g] = (w^T X_g) @ Wv.  192 blocks x 1024 thr:
// 4-way j-split for u, 4-way k-split for the epilogue; LDS reductions.
// ---------------------------------------------------------------------------
__global__ __launch_bounds__(1024) void vout_k(const float* __restrict__ X,
                                               const int* __restrict__ starts,
                                               const float* __restrict__ wbuf,
                                               const float* __restrict__ Wv,
                                               float* __restrict__ out) {
  __shared__ float part[4][256];
  __shared__ float Us[256];
  const int g   = blockIdx.x;
  const int tid = threadIdx.x;
  const int f   = tid & 255;
  const int jp  = tid >> 8;   // 0..3

  const int i0 = starts[g];
  const int n  = starts[g + 1] - i0;

  // u[f] = sum_j w_j * X[i0+j][f]  (j split 4 ways, 2 accumulators each)
  float ua = 0.f, ub = 0.f;
  int j = jp;
  for (; j + 4 < n; j += 8) {
    ua = fmaf(wbuf[i0 + j],     X[(size_t)(i0 + j) * N_FEAT + f], ua);
    ub = fmaf(wbuf[i0 + j + 4], X[(size_t)(i0 + j + 4) * N_FEAT + f], ub);
  }
  for (; j < n; j += 4)
    ua = fmaf(wbuf[i0 + j], X[(size_t)(i0 + j) * N_FEAT + f], ua);
  part[jp][f] = ua + ub;
  __syncthreads();
  if (jp == 0)
    Us[f] = (part[0][f] + part[1][f]) + (part[2][f] + part[3][f]);
  __syncthreads();

  // out[f] = sum_k u_k * Wv[k][f]  (k split 4 ways x 64, 4 accumulators)
  const int k0 = jp * 64;
  const float* wp = Wv + (size_t)k0 * N_FEAT + f;
  const float* us = &Us[k0];
  float a0 = 0.f, a1 = 0.f, a2 = 0.f, a3 = 0.f;
#pragma unroll 4
  for (int k = 0; k < 64; k += 4) {
    a0 = fmaf(us[k],     wp[(size_t)k * N_FEAT], a0);
    a1 = fmaf(us[k + 1], wp[(size_t)(k + 1) * N_FEAT], a1);
    a2 = fmaf(us[k + 2], wp[(size_t)(k + 2) * N_FEAT], a2);
    a3 = fmaf(us[k + 3], wp[(size_t)(k + 3) * N_FEAT], a3);
  }
  __syncthreads();
  part[jp][f] = (a0 + a1) + (a2 + a3);
  __syncthreads();
  if (jp == 0)
    out[g * N_FEAT + f] = (part[0][f] + part[1][f]) + (part[2][f] + part[3][f]);
}

// ---------------------------------------------------------------------------
extern "C" void kernel_launch(void* const* d_in, const int* in_sizes, int n_in,
                              void* d_out, int out_size, void* d_ws, size_t ws_size,
                              hipStream_t stream) {
  const float* X     = (const float*)d_in[0];
  const int*   batch = (const int*)d_in[1];
  const float* Wq    = (const float*)d_in[2];
  const float* Wk    = (const float*)d_in[3];
  const float* Wv    = (const float*)d_in[4];
  float* out = (float*)d_out;

  char* ws = (char*)d_ws;
  int*      starts = (int*)(ws + WS_STARTS);
  float*    wbuf   = (float*)(ws + WS_WBUF);
  float*    Qg     = (float*)(ws + WS_QG);
  unsigned* Kb     = (unsigned*)(ws + WS_KB);
  unsigned* Wt     = (unsigned*)(ws + WS_WT);

  hipMemsetAsync(wbuf, 0, N_NODES * 4, stream);
  seg_starts_k<<<1, 256, 0, stream>>>(batch, starts);
  wt_prep_k<<<256, 64, 0, stream>>>(Wq, Wk, Wt);
  qk_proj_k<<<N_NODES / MT, 256, 0, stream>>>(X, Wt, Qg, Kb);
  attn_w_k<<<N_GRAPHS * NSL, 256, 0, stream>>>(starts, Qg, Kb, wbuf);
  vout_k<<<N_GRAPHS, 1024, 0, stream>>>(X, starts, wbuf, Wv, out);
}

// Round 6
// 99.550 us; speedup vs baseline: 3.0589x; 3.0589x over previous
//
#include <hip/hip_runtime.h>
#include <hip/hip_bf16.h>

#define N_NODES  12288
#define N_FEAT   256
#define KDIM     128
#define N_GRAPHS 192
#define NMAX     112          // LDS fast-path max graph size (mean 64, std ~8)
#define KSTRIDE_U 68          // K LDS row stride in u32 (272 B; 4j mod 32 -> 2-way=free)

// qk_proj MFMA tile params
#define MT   32               // rows per block
#define XS_STRIDE_U 36        // X LDS row stride in u32 (72 bf16; 36%32=4 -> balanced)
#define WT_STRIDE_U 36        // Wt LDS row stride in u32

// workspace layout (bytes)
#define WS_STARTS 0
#define WS_WBUF   1024                                  // fp32 w [12288]
#define WS_U      (WS_WBUF + N_NODES * 4)               // fp32 U [192][256]
#define WS_QB     (WS_U + N_GRAPHS * N_FEAT * 4)        // bf16 Q [12288][128] as u32[64]
#define WS_KB     (WS_QB + N_NODES * 64 * 4)            // bf16 K [12288][128] as u32[64]
#define WS_WT     (WS_KB + N_NODES * 64 * 4)            // bf16 Wt [256][256] as u32[128]

typedef __bf16 bf16x8 __attribute__((ext_vector_type(8)));
typedef float  f32x4  __attribute__((ext_vector_type(4)));

__device__ __forceinline__ unsigned bf16_rne(float f) {
  unsigned u = __float_as_uint(f);
  return (u + 0x7FFFu + ((u >> 16) & 1u)) >> 16;
}
__device__ __forceinline__ unsigned pack_bf16(float lo, float hi) {
  return bf16_rne(lo) | (bf16_rne(hi) << 16);
}
__device__ __forceinline__ float bf_lo(unsigned u) { return __uint_as_float(u << 16); }
__device__ __forceinline__ float bf_hi(unsigned u) { return __uint_as_float(u & 0xFFFF0000u); }

// ---------------------------------------------------------------------------
// Kernel 1: segment starts via binary search (batch is sorted).
// ---------------------------------------------------------------------------
__global__ __launch_bounds__(256) void seg_starts_k(const int* __restrict__ batch,
                                                    int* __restrict__ starts) {
  int g = threadIdx.x;
  if (g > N_GRAPHS) return;
  int lo = 0, hi = N_NODES;
  while (lo < hi) {
    int mid = (lo + hi) >> 1;
    if (batch[mid] < g) lo = mid + 1; else hi = mid;
  }
  starts[g] = lo;
}

// ---------------------------------------------------------------------------
// Kernel 1b: W pre-transpose to bf16.  Wt[n][k] packed u32 pairs (k, k+1).
// ---------------------------------------------------------------------------
__global__ __launch_bounds__(64) void wt_prep_k(const float* __restrict__ Wq,
                                                const float* __restrict__ Wk,
                                                unsigned* __restrict__ Wt) {
  const int n = blockIdx.x;
  const int t = threadIdx.x;
  const float* src = (n < KDIM) ? (Wq + n) : (Wk + (n - KDIM));
  float f0 = src[(4 * t + 0) * KDIM];
  float f1 = src[(4 * t + 1) * KDIM];
  float f2 = src[(4 * t + 2) * KDIM];
  float f3 = src[(4 * t + 3) * KDIM];
  Wt[n * 128 + 2 * t]     = pack_bf16(f0, f1);
  Wt[n * 128 + 2 * t + 1] = pack_bf16(f2, f3);
}

// ---------------------------------------------------------------------------
// Kernel 2: fused Q|K projection via bf16 MFMA. Q and K both emitted as
// packed bf16 (Q scaled by 1/16). Waves 0-1 -> Q cols, 2-3 -> K cols.
// ---------------------------------------------------------------------------
__global__ __launch_bounds__(256) void qk_proj_k(const float* __restrict__ X,
                                                 const unsigned* __restrict__ Wt,
                                                 unsigned* __restrict__ Qb,
                                                 unsigned* __restrict__ Kb) {
  __shared__ unsigned Xs_u[MT * XS_STRIDE_U];      // 4608 B
  __shared__ unsigned Ws_u[256 * WT_STRIDE_U];     // 36864 B

  const int tid  = threadIdx.x;
  const int lane = tid & 63;
  const int wv   = tid >> 6;
  const int r0   = blockIdx.x * MT;
  const int l15  = lane & 15;
  const int quad = lane >> 4;

  f32x4 acc[2][4];
#pragma unroll
  for (int mi = 0; mi < 2; mi++)
#pragma unroll
    for (int ni = 0; ni < 4; ni++) acc[mi][ni] = (f32x4){0.f, 0.f, 0.f, 0.f};

  for (int c = 0; c < 4; c++) {
    const int k0 = c * 64;
    if (c) __syncthreads();

    {
      const int row = tid >> 3, c8 = tid & 7;
      const float* xp = &X[(size_t)(r0 + row) * N_FEAT + k0 + c8 * 8];
      float4 a = *(const float4*)xp;
      float4 b = *(const float4*)(xp + 4);
      unsigned p0 = pack_bf16(a.x, a.y), p1 = pack_bf16(a.z, a.w);
      unsigned p2 = pack_bf16(b.x, b.y), p3 = pack_bf16(b.z, b.w);
      *(uint4*)&Xs_u[row * XS_STRIDE_U + c8 * 4] = make_uint4(p0, p1, p2, p3);
    }
#pragma unroll
    for (int it = 0; it < 8; it++) {
      const int i = tid + it * 256;
      const int n = i >> 3, c8 = i & 7;
      uint4 w = *(const uint4*)&Wt[n * 128 + k0 / 2 + c8 * 4];
      *(uint4*)&Ws_u[n * WT_STRIDE_U + c8 * 4] = w;
    }
    __syncthreads();

#pragma unroll
    for (int ks = 0; ks < 2; ks++) {
      const int ko = ks * 16 + quad * 4;
      bf16x8 a[2], b[4];
#pragma unroll
      for (int mi = 0; mi < 2; mi++)
        a[mi] = *(const bf16x8*)&Xs_u[(mi * 16 + l15) * XS_STRIDE_U + ko];
#pragma unroll
      for (int ni = 0; ni < 4; ni++)
        b[ni] = *(const bf16x8*)&Ws_u[(wv * 64 + ni * 16 + l15) * WT_STRIDE_U + ko];
#pragma unroll
      for (int mi = 0; mi < 2; mi++)
#pragma unroll
        for (int ni = 0; ni < 4; ni++)
          acc[mi][ni] = __builtin_amdgcn_mfma_f32_16x16x32_bf16(a[mi], b[ni], acc[mi][ni], 0, 0, 0);
    }
  }

  // epilogue: C/D layout col = lane&15, row = quad*4 + e; pack bf16 pairs
  unsigned* dst = (wv < 2) ? Qb : Kb;
  const float scale = (wv < 2) ? 0.0625f : 1.0f;
  const int colbase = (wv & 1) * 64;
#pragma unroll
  for (int mi = 0; mi < 2; mi++)
#pragma unroll
    for (int ni = 0; ni < 4; ni++) {
      const int col = colbase + ni * 16 + l15;
#pragma unroll
      for (int e = 0; e < 4; e++) {
        const int row = r0 + mi * 16 + quad * 4 + e;
        unsigned b = bf16_rne(acc[mi][ni][e] * scale);
        unsigned partner = __shfl_xor((int)b, 1);
        if ((lane & 1) == 0)
          dst[row * 64 + (col >> 1)] = b | (partner << 16);
      }
    }
}

// ---------------------------------------------------------------------------
// Kernel 3: column weights of softmax(QK^T) via MFMA.
// 2 blocks/graph (strip parity) x 256 thr. Each wave: one 16-row strip x
// 7 col-groups (n padded to 112): 28 mfma_16x16x32_bf16. Softmax on C-layout
// frags: row = quad*4+e -> quad-local shfl_xor{1,2,4,8}; column weights
// reduced shfl_xor{16,32} -> LDS -> one atomicAdd per column.
// Slow path (n > NMAX): qi==0 block, global bf16 K/Q, two-pass softmax.
// ---------------------------------------------------------------------------
__global__ __launch_bounds__(256) void attn_w_k(const int* __restrict__ starts,
                                                const unsigned* __restrict__ Qb,
                                                const unsigned* __restrict__ Kb,
                                                float* __restrict__ wbuf) {
  __shared__ unsigned Ks_u[NMAX * KSTRIDE_U];   // 30464 B
  __shared__ float    w_lds[4][NMAX];           // 1792 B

  const int tid  = threadIdx.x;
  const int lane = tid & 63;
  const int wv   = tid >> 6;
  const int l15  = lane & 15;
  const int quad = lane >> 4;
  const int g    = blockIdx.x >> 1;
  const int qi   = blockIdx.x & 1;

  const int i0 = starts[g];
  const int n  = starts[g + 1] - i0;
  const float BIG = 1e30f;
  const bool fast = (n <= NMAX);
  if (!fast && qi != 0) return;

  float wl[7];
#pragma unroll
  for (int f = 0; f < 7; f++) wl[f] = 0.f;

  if (fast) {
    // ---- stage K tile (bf16 packed) ----
    for (int idx = tid; idx < n * 16; idx += 256) {
      int j = idx >> 4, c = idx & 15;
      *(uint4*)&Ks_u[j * KSTRIDE_U + 4 * c] = *(const uint4*)&Kb[(size_t)(i0 + j) * 64 + 4 * c];
    }
    __syncthreads();

    const int ns = (n + 15) >> 4;        // strips
    const int s  = qi + 2 * wv;          // this wave's strip (parity qi)

    if (s < ns && n > 0) {
      // ---- A frags: Q rows from global (bf16) ----
      const int arow = min(s * 16 + l15, n - 1);
      const unsigned* qrow = &Qb[(size_t)(i0 + arow) * 64];
      bf16x8 au[4];
#pragma unroll
      for (int ks = 0; ks < 4; ks++)
        au[ks] = *(const bf16x8*)&qrow[ks * 16 + quad * 4];

      // ---- scores: 7 col-groups x 4 k-steps ----
      f32x4 acc[7];
#pragma unroll
      for (int f = 0; f < 7; f++) acc[f] = (f32x4){0.f, 0.f, 0.f, 0.f};
#pragma unroll
      for (int f = 0; f < 7; f++) {
#pragma unroll
        for (int ks = 0; ks < 4; ks++) {
          bf16x8 bu = *(const bf16x8*)&Ks_u[(f * 16 + l15) * KSTRIDE_U + ks * 16 + quad * 4];
          acc[f] = __builtin_amdgcn_mfma_f32_16x16x32_bf16(au[ks], bu, acc[f], 0, 0, 0);
        }
      }

      // ---- mask invalid columns ----
      const bool colv = true;
#pragma unroll
      for (int f = 0; f < 7; f++) {
        if (f * 16 + l15 >= n) {
          acc[f][0] = -BIG; acc[f][1] = -BIG; acc[f][2] = -BIG; acc[f][3] = -BIG;
        }
      }
      (void)colv;

      // ---- softmax per row (row = s*16 + quad*4 + e), accumulate w ----
#pragma unroll
      for (int e = 0; e < 4; e++) {
        float m = -BIG;
#pragma unroll
        for (int f = 0; f < 7; f++) m = fmaxf(m, acc[f][e]);
        m = fmaxf(m, __shfl_xor(m, 1));
        m = fmaxf(m, __shfl_xor(m, 2));
        m = fmaxf(m, __shfl_xor(m, 4));
        m = fmaxf(m, __shfl_xor(m, 8));
        float p[7], l = 0.f;
#pragma unroll
        for (int f = 0; f < 7; f++) { p[f] = __expf(acc[f][e] - m); l += p[f]; }
        l += __shfl_xor(l, 1);
        l += __shfl_xor(l, 2);
        l += __shfl_xor(l, 4);
        l += __shfl_xor(l, 8);
        const int row = s * 16 + quad * 4 + e;
        float inv = (row < n) ? (1.f / l) : 0.f;
#pragma unroll
        for (int f = 0; f < 7; f++) wl[f] = fmaf(p[f], inv, wl[f]);
      }
    }

    // ---- reduce across quads (same column j = f*16+l15) ----
#pragma unroll
    for (int f = 0; f < 7; f++) {
      wl[f] += __shfl_xor(wl[f], 16);
      wl[f] += __shfl_xor(wl[f], 32);
    }
    if (lane < 16) {
#pragma unroll
      for (int f = 0; f < 7; f++) w_lds[wv][f * 16 + lane] = wl[f];
    }
    __syncthreads();

    if (tid < n && tid < NMAX) {
      float t = w_lds[0][tid] + w_lds[1][tid] + w_lds[2][tid] + w_lds[3][tid];
      atomicAdd(&wbuf[i0 + tid], t);
    }
  } else {
    // ---- slow path: whole graph, global bf16 Q/K, two-pass softmax ----
    for (int lr = wv; lr < n; lr += 4) {
      const uint4* qp4 = (const uint4*)&Qb[(size_t)(i0 + lr) * 64];
      float m_run = -BIG, l_run = 0.f;
      for (int jb = 0; jb < n; jb += 64) {
        int j = jb + lane;
        int jc = min(j, n - 1);
        const uint4* kp4 = (const uint4*)&Kb[(size_t)(i0 + jc) * 64];
        float s = 0.f;
        for (int c = 0; c < 16; c++) {
          uint4 Q1 = qp4[c];
          uint4 K1 = kp4[c];
          s = fmaf(bf_lo(Q1.x), bf_lo(K1.x), s); s = fmaf(bf_hi(Q1.x), bf_hi(K1.x), s);
          s = fmaf(bf_lo(Q1.y), bf_lo(K1.y), s); s = fmaf(bf_hi(Q1.y), bf_hi(K1.y), s);
          s = fmaf(bf_lo(Q1.z), bf_lo(K1.z), s); s = fmaf(bf_hi(Q1.z), bf_hi(K1.z), s);
          s = fmaf(bf_lo(Q1.w), bf_lo(K1.w), s); s = fmaf(bf_hi(Q1.w), bf_hi(K1.w), s);
        }
        if (j >= n) s = -BIG;
        float mc = s;
        for (int off = 32; off; off >>= 1) mc = fmaxf(mc, __shfl_xor(mc, off));
        float m_new = fmaxf(m_run, mc);
        float lc = __expf(s - m_new);
        for (int off = 32; off; off >>= 1) lc += __shfl_xor(lc, off);
        l_run = l_run * __expf(m_run - m_new) + lc;
        m_run = m_new;
      }
      float inv = 1.f / l_run;
      for (int jb = 0; jb < n; jb += 64) {
        int j = jb + lane;
        int jc = min(j, n - 1);
        const uint4* kp4 = (const uint4*)&Kb[(size_t)(i0 + jc) * 64];
        float s = 0.f;
        for (int c = 0; c < 16; c++) {
          uint4 Q1 = qp4[c];
          uint4 K1 = kp4[c];
          s = fmaf(bf_lo(Q1.x), bf_lo(K1.x), s); s = fmaf(bf_hi(Q1.x), bf_hi(K1.x), s);
          s = fmaf(bf_lo(Q1.y), bf_lo(K1.y), s); s = fmaf(bf_hi(Q1.y), bf_hi(K1.y), s);
          s = fmaf(bf_lo(Q1.z), bf_lo(K1.z), s); s = fmaf(bf_hi(Q1.z), bf_hi(K1.z), s);
          s = fmaf(bf_lo(Q1.w), bf_lo(K1.w), s); s = fmaf(bf_hi(Q1.w), bf_hi(K1.w), s);
        }
        if (j < n) atomicAdd(&wbuf[i0 + j], __expf(s - m_run) * inv);
      }
    }
  }
}

// ---------------------------------------------------------------------------
// Kernel 4a: U[g][f] = sum_j w_j * X[i0+j][f].  384 blocks x 512 thr
// (2 f-halves per graph, 4-way j-split, LDS reduce).
// ---------------------------------------------------------------------------
__global__ __launch_bounds__(512) void vout_u_k(const float* __restrict__ X,
                                                const int* __restrict__ starts,
                                                const float* __restrict__ wbuf,
                                                float* __restrict__ U) {
  __shared__ float part[4][128];
  const int g   = blockIdx.x >> 1;
  const int fh  = blockIdx.x & 1;
  const int tid = threadIdx.x;
  const int fl  = tid & 127;
  const int f   = fh * 128 + fl;
  const int jp  = tid >> 7;   // 0..3

  const int i0 = starts[g];
  const int n  = starts[g + 1] - i0;

  float ua = 0.f, ub = 0.f;
  int j = jp;
  for (; j + 4 < n; j += 8) {
    ua = fmaf(wbuf[i0 + j],     X[(size_t)(i0 + j) * N_FEAT + f], ua);
    ub = fmaf(wbuf[i0 + j + 4], X[(size_t)(i0 + j + 4) * N_FEAT + f], ub);
  }
  for (; j < n; j += 4)
    ua = fmaf(wbuf[i0 + j], X[(size_t)(i0 + j) * N_FEAT + f], ua);
  part[jp][fl] = ua + ub;
  __syncthreads();
  if (jp == 0)
    U[g * N_FEAT + f] = (part[0][fl] + part[1][fl]) + (part[2][fl] + part[3][fl]);
}

// ---------------------------------------------------------------------------
// Kernel 4b: out[g] = U[g] @ Wv.  384 blocks x 512 thr (2 f-halves, 4-way k).
// ---------------------------------------------------------------------------
__global__ __launch_bounds__(512) void vout_o_k(const float* __restrict__ U,
                                                const float* __restrict__ Wv,
                                                float* __restrict__ out) {
  __shared__ float Us[256];
  __shared__ float part[4][128];
  const int g   = blockIdx.x >> 1;
  const int fh  = blockIdx.x & 1;
  const int tid = threadIdx.x;
  const int fl  = tid & 127;
  const int f   = fh * 128 + fl;
  const int kq  = tid >> 7;   // 0..3

  if (tid < 256) Us[tid] = U[g * N_FEAT + tid];
  __syncthreads();

  const int k0 = kq * 64;
  const float* wp = Wv + (size_t)k0 * N_FEAT + f;
  const float* us = &Us[k0];
  float a0 = 0.f, a1 = 0.f, a2 = 0.f, a3 = 0.f;
#pragma unroll 4
  for (int k = 0; k < 64; k += 4) {
    a0 = fmaf(us[k],     wp[(size_t)k * N_FEAT], a0);
    a1 = fmaf(us[k + 1], wp[(size_t)(k + 1) * N_FEAT], a1);
    a2 = fmaf(us[k + 2], wp[(size_t)(k + 2) * N_FEAT], a2);
    a3 = fmaf(us[k + 3], wp[(size_t)(k + 3) * N_FEAT], a3);
  }
  part[kq][fl] = (a0 + a1) + (a2 + a3);
  __syncthreads();
  if (kq == 0)
    out[g * N_FEAT + f] = (part[0][fl] + part[1][fl]) + (part[2][fl] + part[3][fl]);
}

// ---------------------------------------------------------------------------
extern "C" void kernel_launch(void* const* d_in, const int* in_sizes, int n_in,
                              void* d_out, int out_size, void* d_ws, size_t ws_size,
                              hipStream_t stream) {
  const float* X     = (const float*)d_in[0];
  const int*   batch = (const int*)d_in[1];
  const float* Wq    = (const float*)d_in[2];
  const float* Wk    = (const float*)d_in[3];
  const float* Wv    = (const float*)d_in[4];
  float* out = (float*)d_out;

  char* ws = (char*)d_ws;
  int*      starts = (int*)(ws + WS_STARTS);
  float*    wbuf   = (float*)(ws + WS_WBUF);
  float*    U      = (float*)(ws + WS_U);
  unsigned* Qb     = (unsigned*)(ws + WS_QB);
  unsigned* Kb     = (unsigned*)(ws + WS_KB);
  unsigned* Wt     = (unsigned*)(ws + WS_WT);

  // zero wbuf + U (contiguous)
  hipMemsetAsync(ws + WS_WBUF, 0, (N_NODES + N_GRAPHS * N_FEAT) * 4, stream);
  seg_starts_k<<<1, 256, 0, stream>>>(batch, starts);
  wt_prep_k<<<256, 64, 0, stream>>>(Wq, Wk, Wt);
  qk_proj_k<<<N_NODES / MT, 256, 0, stream>>>(X, Wt, Qb, Kb);
  attn_w_k<<<N_GRAPHS * 2, 256, 0, stream>>>(starts, Qb, Kb, wbuf);
  vout_u_k<<<N_GRAPHS * 2, 512, 0, stream>>>(X, starts, wbuf, U);
  vout_o_k<<<N_GRAPHS * 2, 512, 0, stream>>>(U, Wv, out);
}

// Round 7
// 98.415 us; speedup vs baseline: 3.0941x; 1.0115x over previous
//
#include <hip/hip_runtime.h>
#include <hip/hip_bf16.h>

#define N_NODES  12288
#define N_FEAT   256
#define KDIM     128
#define N_GRAPHS 192
#define NMAX     112          // LDS fast-path max graph size (mean 64, std ~8)
#define KSTRIDE_U 68          // K LDS row stride in u32 (272 B; 4j mod 32 -> 2-way=free)
#define XS_STRIDE_U 132       // X LDS row stride in u32 (132%32=4 -> 2-way=free; 16B-aligned)

// workspace layout (bytes)
#define WS_STARTS 0
#define WS_WBUF   1024                                  // fp32 w [12288] (slow path only)
#define WS_QB     (WS_WBUF + N_NODES * 4)               // bf16 Q [12288][128] as u32[64]
#define WS_KB     (WS_QB + N_NODES * 64 * 4)            // bf16 K [12288][128] as u32[64]
#define WS_WT     (WS_KB + N_NODES * 64 * 4)            // bf16 Wt [256][256] as u32[128]

typedef __bf16 bf16x8 __attribute__((ext_vector_type(8)));
typedef float  f32x4  __attribute__((ext_vector_type(4)));

__device__ __forceinline__ unsigned bf16_rne(float f) {
  unsigned u = __float_as_uint(f);
  return (u + 0x7FFFu + ((u >> 16) & 1u)) >> 16;
}
__device__ __forceinline__ unsigned pack_bf16(float lo, float hi) {
  return bf16_rne(lo) | (bf16_rne(hi) << 16);
}
__device__ __forceinline__ float bf_lo(unsigned u) { return __uint_as_float(u << 16); }
__device__ __forceinline__ float bf_hi(unsigned u) { return __uint_as_float(u & 0xFFFF0000u); }

// ---------------------------------------------------------------------------
// Kernel 1: W pre-transpose to bf16 (Wt[n][k], packed u32 pairs) + segment
// starts (block n <= 192: starts[n] = lower_bound(batch, n); batch sorted).
// ---------------------------------------------------------------------------
__global__ __launch_bounds__(64) void wt_prep_k(const float* __restrict__ Wq,
                                                const float* __restrict__ Wk,
                                                const int* __restrict__ batch,
                                                unsigned* __restrict__ Wt,
                                                int* __restrict__ starts) {
  const int n = blockIdx.x;
  const int t = threadIdx.x;
  const float* src = (n < KDIM) ? (Wq + n) : (Wk + (n - KDIM));
  float f0 = src[(4 * t + 0) * KDIM];
  float f1 = src[(4 * t + 1) * KDIM];
  float f2 = src[(4 * t + 2) * KDIM];
  float f3 = src[(4 * t + 3) * KDIM];
  Wt[n * 128 + 2 * t]     = pack_bf16(f0, f1);
  Wt[n * 128 + 2 * t + 1] = pack_bf16(f2, f3);

  if (t == 0 && n <= N_GRAPHS) {
    int lo = 0, hi = N_NODES;
    while (lo < hi) {
      int mid = (lo + hi) >> 1;
      if (batch[mid] < n) lo = mid + 1; else hi = mid;
    }
    starts[n] = lo;
  }
}

// ---------------------------------------------------------------------------
// Kernel 2: fused Q|K projection via bf16 MFMA. M-tile 16 -> 768 blocks x
// 256 thr. X staged once (full K=256, 8.5 KB LDS, ONE barrier); W B-frags
// read directly from global Wt (128 KB, L2-resident; each frag = 16 rows x
// 64 contiguous bytes). Wave wv owns cols 64wv..64wv+63: waves 0-1 -> Q
// (scaled 1/16), 2-3 -> K. Both outputs packed bf16.
// ---------------------------------------------------------------------------
__global__ __launch_bounds__(256) void qk_proj_k(const float* __restrict__ X,
                                                 const unsigned* __restrict__ Wt,
                                                 unsigned* __restrict__ Qb,
                                                 unsigned* __restrict__ Kb) {
  __shared__ unsigned Xs_u[16 * XS_STRIDE_U];   // 8448 B

  const int tid  = threadIdx.x;
  const int lane = tid & 63;
  const int wv   = tid >> 6;
  const int r0   = blockIdx.x * 16;
  const int l15  = lane & 15;
  const int quad = lane >> 4;

  // ---- stage X tile: 16 rows x 256 k, fp32 -> bf16, one shot ----
  {
    const int row = tid >> 4, seg = tid & 15;   // 8 u32 (16 bf16) per thread
    const float* xp = &X[(size_t)(r0 + row) * N_FEAT + seg * 16];
    float4 a = *(const float4*)xp;
    float4 b = *(const float4*)(xp + 4);
    float4 c = *(const float4*)(xp + 8);
    float4 d = *(const float4*)(xp + 12);
    unsigned* dst = &Xs_u[row * XS_STRIDE_U + seg * 8];
    *(uint4*)dst       = make_uint4(pack_bf16(a.x, a.y), pack_bf16(a.z, a.w),
                                    pack_bf16(b.x, b.y), pack_bf16(b.z, b.w));
    *(uint4*)(dst + 4) = make_uint4(pack_bf16(c.x, c.y), pack_bf16(c.z, c.w),
                                    pack_bf16(d.x, d.y), pack_bf16(d.z, d.w));
  }
  __syncthreads();

  f32x4 acc[4];
#pragma unroll
  for (int ni = 0; ni < 4; ni++) acc[ni] = (f32x4){0.f, 0.f, 0.f, 0.f};

#pragma unroll
  for (int ks = 0; ks < 8; ks++) {
    bf16x8 a = *(const bf16x8*)&Xs_u[l15 * XS_STRIDE_U + ks * 16 + quad * 4];
    bf16x8 b[4];
#pragma unroll
    for (int ni = 0; ni < 4; ni++)
      b[ni] = *(const bf16x8*)&Wt[(size_t)(wv * 64 + ni * 16 + l15) * 128 + ks * 16 + quad * 4];
#pragma unroll
    for (int ni = 0; ni < 4; ni++)
      acc[ni] = __builtin_amdgcn_mfma_f32_16x16x32_bf16(a, b[ni], acc[ni], 0, 0, 0);
  }

  // ---- epilogue: C/D col = lane&15, row = quad*4 + e; pack bf16 pairs ----
  unsigned* dst = (wv < 2) ? Qb : Kb;
  const float scale = (wv < 2) ? 0.0625f : 1.0f;
  const int colbase = (wv & 1) * 64;
#pragma unroll
  for (int ni = 0; ni < 4; ni++) {
    const int col = colbase + ni * 16 + l15;
#pragma unroll
    for (int e = 0; e < 4; e++) {
      const int row = r0 + quad * 4 + e;
      unsigned b = bf16_rne(acc[ni][e] * scale);
      unsigned partner = __shfl_xor((int)b, 1);
      if ((lane & 1) == 0)
        dst[row * 64 + (col >> 1)] = b | (partner << 16);
    }
  }
}

// ---------------------------------------------------------------------------
// Kernel 3: fused attention pooling — one 512-thr block (8 waves) per graph.
// Phase A: stage K tile (bf16, stride-68) -> wave s computes 16-row strip s
//   (7 col-groups x 4 k-steps = 28 MFMA) -> in-wave softmax (quad shfl) ->
//   column weights reduced shfl{16,32} -> w_lds.
// Phase B: w2 = sum over waves; u[f] = sum_j w2[j] X[i0+j][f] (2-way j-split);
//   out[g] = u @ Wv (2-way k-split). All in-block, no atomics, no memset.
// Slow path (n > NMAX): block zeroes its own wbuf segment, two-pass online
// softmax into wbuf via atomics (single block per graph -> race-free).
// ---------------------------------------------------------------------------
__global__ __launch_bounds__(512) void attn_pool_k(const float* __restrict__ X,
                                                   const int* __restrict__ starts,
                                                   const unsigned* __restrict__ Qb,
                                                   const unsigned* __restrict__ Kb,
                                                   const float* __restrict__ Wv,
                                                   float* __restrict__ out,
                                                   float* __restrict__ wbuf) {
  __shared__ unsigned Ks_u[NMAX * KSTRIDE_U];   // 30464 B
  __shared__ float    w_lds[8][NMAX];           // 3584 B
  __shared__ float    red[2][256];              // 2048 B
  __shared__ float    Us[256];                  // 1024 B

  const int tid  = threadIdx.x;
  const int lane = tid & 63;
  const int wv   = tid >> 6;
  const int l15  = lane & 15;
  const int quad = lane >> 4;
  const int g    = blockIdx.x;

  const int i0 = starts[g];
  const int n  = starts[g + 1] - i0;
  const float BIG = 1e30f;
  const bool fast = (n <= NMAX);

  if (fast) {
    // ---- stage K tile ----
    for (int idx = tid; idx < n * 16; idx += 512) {
      int j = idx >> 4, c = idx & 15;
      *(uint4*)&Ks_u[j * KSTRIDE_U + 4 * c] = *(const uint4*)&Kb[(size_t)(i0 + j) * 64 + 4 * c];
    }
    __syncthreads();

    float wl[7];
#pragma unroll
    for (int f = 0; f < 7; f++) wl[f] = 0.f;

    const int ns = (n + 15) >> 4;   // strips; wave s handles strip s
    if (wv < ns) {
      const int s = wv;
      const int arow = min(s * 16 + l15, n - 1);
      const unsigned* qrow = &Qb[(size_t)(i0 + arow) * 64];
      bf16x8 au[4];
#pragma unroll
      for (int ks = 0; ks < 4; ks++)
        au[ks] = *(const bf16x8*)&qrow[ks * 16 + quad * 4];

      f32x4 acc[7];
#pragma unroll
      for (int f = 0; f < 7; f++) acc[f] = (f32x4){0.f, 0.f, 0.f, 0.f};
#pragma unroll
      for (int f = 0; f < 7; f++) {
#pragma unroll
        for (int ks = 0; ks < 4; ks++) {
          bf16x8 bu = *(const bf16x8*)&Ks_u[(f * 16 + l15) * KSTRIDE_U + ks * 16 + quad * 4];
          acc[f] = __builtin_amdgcn_mfma_f32_16x16x32_bf16(au[ks], bu, acc[f], 0, 0, 0);
        }
      }
#pragma unroll
      for (int f = 0; f < 7; f++)
        if (f * 16 + l15 >= n) {
          acc[f][0] = -BIG; acc[f][1] = -BIG; acc[f][2] = -BIG; acc[f][3] = -BIG;
        }

#pragma unroll
      for (int e = 0; e < 4; e++) {
        float m = -BIG;
#pragma unroll
        for (int f = 0; f < 7; f++) m = fmaxf(m, acc[f][e]);
        m = fmaxf(m, __shfl_xor(m, 1));
        m = fmaxf(m, __shfl_xor(m, 2));
        m = fmaxf(m, __shfl_xor(m, 4));
        m = fmaxf(m, __shfl_xor(m, 8));
        float p[7], l = 0.f;
#pragma unroll
        for (int f = 0; f < 7; f++) { p[f] = __expf(acc[f][e] - m); l += p[f]; }
        l += __shfl_xor(l, 1);
        l += __shfl_xor(l, 2);
        l += __shfl_xor(l, 4);
        l += __shfl_xor(l, 8);
        const int row = s * 16 + quad * 4 + e;
        float inv = (row < n) ? (1.f / l) : 0.f;
#pragma unroll
        for (int f = 0; f < 7; f++) wl[f] = fmaf(p[f], inv, wl[f]);
      }
    }

    // ---- reduce across quads (column j = f*16 + l15) ----
#pragma unroll
    for (int f = 0; f < 7; f++) {
      wl[f] += __shfl_xor(wl[f], 16);
      wl[f] += __shfl_xor(wl[f], 32);
    }
    if (lane < 16) {
#pragma unroll
      for (int f = 0; f < 7; f++) w_lds[wv][f * 16 + lane] = wl[f];
    }
    __syncthreads();

    // ---- w2[j] = sum over 8 waves ----
    if (tid < NMAX) {
      float t = 0.f;
#pragma unroll
      for (int k = 0; k < 8; k++) t += w_lds[k][tid];
      w_lds[0][tid] = t;
    }
    __syncthreads();
  } else {
    // ---- slow path: zero own wbuf segment, two-pass online softmax ----
    for (int idx = tid; idx < n; idx += 512) wbuf[i0 + idx] = 0.f;
    __syncthreads();
    for (int lr = wv; lr < n; lr += 8) {
      const uint4* qp4 = (const uint4*)&Qb[(size_t)(i0 + lr) * 64];
      float m_run = -BIG, l_run = 0.f;
      for (int jb = 0; jb < n; jb += 64) {
        int j = jb + lane;
        int jc = min(j, n - 1);
        const uint4* kp4 = (const uint4*)&Kb[(size_t)(i0 + jc) * 64];
        float s = 0.f;
        for (int c = 0; c < 16; c++) {
          uint4 Q1 = qp4[c];
          uint4 K1 = kp4[c];
          s = fmaf(bf_lo(Q1.x), bf_lo(K1.x), s); s = fmaf(bf_hi(Q1.x), bf_hi(K1.x), s);
          s = fmaf(bf_lo(Q1.y), bf_lo(K1.y), s); s = fmaf(bf_hi(Q1.y), bf_hi(K1.y), s);
          s = fmaf(bf_lo(Q1.z), bf_lo(K1.z), s); s = fmaf(bf_hi(Q1.z), bf_hi(K1.z), s);
          s = fmaf(bf_lo(Q1.w), bf_lo(K1.w), s); s = fmaf(bf_hi(Q1.w), bf_hi(K1.w), s);
        }
        if (j >= n) s = -BIG;
        float mc = s;
        for (int off = 32; off; off >>= 1) mc = fmaxf(mc, __shfl_xor(mc, off));
        float m_new = fmaxf(m_run, mc);
        float lc = __expf(s - m_new);
        for (int off = 32; off; off >>= 1) lc += __shfl_xor(lc, off);
        l_run = l_run * __expf(m_run - m_new) + lc;
        m_run = m_new;
      }
      float inv = 1.f / l_run;
      for (int jb = 0; jb < n; jb += 64) {
        int j = jb + lane;
        int jc = min(j, n - 1);
        const uint4* kp4 = (const uint4*)&Kb[(size_t)(i0 + jc) * 64];
        float s = 0.f;
        for (int c = 0; c < 16; c++) {
          uint4 Q1 = qp4[c];
          uint4 K1 = kp4[c];
          s = fmaf(bf_lo(Q1.x), bf_lo(K1.x), s); s = fmaf(bf_hi(Q1.x), bf_hi(K1.x), s);
          s = fmaf(bf_lo(Q1.y), bf_lo(K1.y), s); s = fmaf(bf_hi(Q1.y), bf_hi(K1.y), s);
          s = fmaf(bf_lo(Q1.z), bf_lo(K1.z), s); s = fmaf(bf_hi(Q1.z), bf_hi(K1.z), s);
          s = fmaf(bf_lo(Q1.w), bf_lo(K1.w), s); s = fmaf(bf_hi(Q1.w), bf_hi(K1.w), s);
        }
        if (j < n) atomicAdd(&wbuf[i0 + j], __expf(s - m_run) * inv);
      }
    }
    __threadfence();
    __syncthreads();
  }

  // ---- u[f] = sum_j w[j] * X[i0+j][f]  (2-way j-split) ----
  const int f  = tid & 255;
  const int jp = tid >> 8;
  float ua = 0.f, ub = 0.f;
  if (fast) {
    int j = jp;
    for (; j + 2 < n; j += 4) {
      ua = fmaf(w_lds[0][j],     X[(size_t)(i0 + j) * N_FEAT + f], ua);
      ub = fmaf(w_lds[0][j + 2], X[(size_t)(i0 + j + 2) * N_FEAT + f], ub);
    }
    for (; j < n; j += 2)
      ua = fmaf(w_lds[0][j], X[(size_t)(i0 + j) * N_FEAT + f], ua);
  } else {
    for (int j = jp; j < n; j += 2) {
      float wj = atomicAdd(&wbuf[i0 + j], 0.f);   // coherent read past L1
      ua = fmaf(wj, X[(size_t)(i0 + j) * N_FEAT + f], ua);
    }
  }
  red[jp][f] = ua + ub;
  __syncthreads();
  if (jp == 0) Us[f] = red[0][f] + red[1][f];
  __syncthreads();

  // ---- out[g][f] = sum_k u_k * Wv[k][f]  (2-way k-split) ----
  const int k0 = jp * 128;
  const float* wp = Wv + (size_t)k0 * N_FEAT + f;
  const float* us = &Us[k0];
  float a0 = 0.f, a1 = 0.f, a2 = 0.f, a3 = 0.f;
#pragma unroll 8
  for (int k = 0; k < 128; k += 4) {
    a0 = fmaf(us[k],     wp[(size_t)k * N_FEAT], a0);
    a1 = fmaf(us[k + 1], wp[(size_t)(k + 1) * N_FEAT], a1);
    a2 = fmaf(us[k + 2], wp[(size_t)(k + 2) * N_FEAT], a2);
    a3 = fmaf(us[k + 3], wp[(size_t)(k + 3) * N_FEAT], a3);
  }
  __syncthreads();
  red[jp][f] = (a0 + a1) + (a2 + a3);
  __syncthreads();
  if (jp == 0) out[g * N_FEAT + f] = red[0][f] + red[1][f];
}

// ---------------------------------------------------------------------------
extern "C" void kernel_launch(void* const* d_in, const int* in_sizes, int n_in,
                              void* d_out, int out_size, void* d_ws, size_t ws_size,
                              hipStream_t stream) {
  const float* X     = (const float*)d_in[0];
  const int*   batch = (const int*)d_in[1];
  const float* Wq    = (const float*)d_in[2];
  const float* Wk    = (const float*)d_in[3];
  const float* Wv    = (const float*)d_in[4];
  float* out = (float*)d_out;

  char* ws = (char*)d_ws;
  int*      starts = (int*)(ws + WS_STARTS);
  float*    wbuf   = (float*)(ws + WS_WBUF);
  unsigned* Qb     = (unsigned*)(ws + WS_QB);
  unsigned* Kb     = (unsigned*)(ws + WS_KB);
  unsigned* Wt     = (unsigned*)(ws + WS_WT);

  wt_prep_k<<<256, 64, 0, stream>>>(Wq, Wk, batch, Wt, starts);
  qk_proj_k<<<N_NODES / 16, 256, 0, stream>>>(X, Wt, Qb, Kb);
  attn_pool_k<<<N_GRAPHS, 512, 0, stream>>>(X, starts, Qb, Kb, Wv, out, wbuf);
}